// Round 1
// baseline (555.912 us; speedup 1.0000x reference)
//
#include <hip/hip_runtime.h>
#include <cstdint>
#include <cstddef>

#define IN_F 768
#define HID  64
#define NNZ1 4915
#define NNZ2 409
#define NNZ3 32
#define BATCH 131072

// ---- workspace layout (bytes) ----
// W1 dense fp32 [768][64], W2 dense fp32 [64][64], W3 dense fp32 [64],
// then bf16 MFMA B-fragment layouts for W1 (24 ksteps x 4 ntiles x 64 lanes x 8 bf16)
// and W2 (2 x 4 x 64 x 8).
#define OFF_W1D 0u
#define OFF_W2D 196608u          // 768*64*4
#define OFF_W3D 212992u          // +64*64*4
#define OFF_W1F 213248u          // +256 (W3 padded)
#define OFF_W2F 311552u          // +24*4*64*16
#define WS_NEED 319744u

typedef __bf16 bf16x8 __attribute__((ext_vector_type(8)));
typedef float  f32x4  __attribute__((ext_vector_type(4)));

union FragU { bf16x8 v; uint32_t u[4]; uint4 q; };

__device__ __forceinline__ uint32_t f2bf1(float f) {
    uint32_t u = __float_as_uint(f);
    return (u + 0x7FFFu + ((u >> 16) & 1u)) >> 16;   // RNE
}
__device__ __forceinline__ uint32_t f2bf2(float lo, float hi) {
    uint32_t a = __float_as_uint(lo);
    uint32_t b = __float_as_uint(hi);
    a = a + 0x7FFFu + ((a >> 16) & 1u);
    b = b + 0x7FFFu + ((b >> 16) & 1u);
    return (a >> 16) | (b & 0xFFFF0000u);
}

// ---- COO -> dense scatter (duplicates accumulate, torch coalesce semantics) ----
__global__ void scatter_coo(const int* __restrict__ idx1, const float* __restrict__ val1,
                            const int* __restrict__ idx2, const float* __restrict__ val2,
                            const int* __restrict__ idx3, const float* __restrict__ val3,
                            float* __restrict__ W1d, float* __restrict__ W2d,
                            float* __restrict__ W3d) {
    int t = blockIdx.x * blockDim.x + threadIdx.x;
    if (t < NNZ1) {
        int r = idx1[t], c = idx1[NNZ1 + t];
        atomicAdd(&W1d[r * HID + c], val1[t]);
    } else if (t < NNZ1 + NNZ2) {
        int i = t - NNZ1;
        int r = idx2[i], c = idx2[NNZ2 + i];
        atomicAdd(&W2d[r * HID + c], val2[i]);
    } else if (t < NNZ1 + NNZ2 + NNZ3) {
        int i = t - NNZ1 - NNZ2;
        int r = idx3[i], c = idx3[NNZ3 + i];
        atomicAdd(&W3d[r * 1 + c], val3[i]);   // OUT==1 -> c==0
    }
}

// ---- dense fp32 -> bf16 MFMA B-fragment layout ----
// B operand of mfma_f32_16x16x32_bf16: lane holds B[k = (lane>>4)*8 + j][n = lane&15],
// j = 0..7 contiguous -> store 16B per lane, fully coalesced per frag.
__global__ void frag_build(const float* __restrict__ W1d, const float* __restrict__ W2d,
                           uint4* __restrict__ W1f, uint4* __restrict__ W2f) {
    int t = blockIdx.x * blockDim.x + threadIdx.x;
    const int n1 = 24 * 4 * 64;
    const int n2 = 2 * 4 * 64;
    if (t < n1) {
        int lane = t & 63;
        int fi = t >> 6;
        int kstep = fi >> 2, nt = fi & 3;
        int m = lane & 15, quad = lane >> 4;
        uint32_t u[4];
#pragma unroll
        for (int jj = 0; jj < 4; ++jj) {
            int k = kstep * 32 + quad * 8 + jj * 2;
            u[jj] = f2bf2(W1d[k * HID + nt * 16 + m], W1d[(k + 1) * HID + nt * 16 + m]);
        }
        W1f[t] = make_uint4(u[0], u[1], u[2], u[3]);
    } else if (t < n1 + n2) {
        int tt = t - n1;
        int lane = tt & 63;
        int fi = tt >> 6;
        int kstep = fi >> 2, nt = fi & 3;
        int m = lane & 15, quad = lane >> 4;
        uint32_t u[4];
#pragma unroll
        for (int jj = 0; jj < 4; ++jj) {
            int k = kstep * 32 + quad * 8 + jj * 2;
            u[jj] = f2bf2(W2d[k * HID + nt * 16 + m], W2d[(k + 1) * HID + nt * 16 + m]);
        }
        W2f[tt] = make_uint4(u[0], u[1], u[2], u[3]);
    }
}

// ---- fused 3-layer MLP ----
// Block = 256 threads = 4 waves; each wave computes 16 batch rows.
// Layer 1: 24 K-steps of mfma 16x16x32 over 4 N-tiles (HID=64).
// Layer 2: h1 -> LDS (C-layout -> A-layout round trip), 2 K-steps x 4 N-tiles.
// Layer 3: fp32 dot with dense W3 + 16-lane butterfly reduce.
__global__ __launch_bounds__(256) void mlp_fused(
    const float* __restrict__ x,
    const uint4* __restrict__ W1f,
    const uint4* __restrict__ W2f,
    const float* __restrict__ W3d,
    const float* __restrict__ b1,
    const float* __restrict__ b2,
    const float* __restrict__ b3,
    float* __restrict__ out)
{
    // row stride 72 u16 = 144 B: 16B-aligned for ds_read_b128, breaks pow2 bank pattern
    __shared__ __align__(16) uint16_t h1s[4][16][72];

    const int lane = threadIdx.x & 63;
    const int w    = threadIdx.x >> 6;
    const int m    = lane & 15;
    const int quad = lane >> 4;
    const int rowbase = blockIdx.x * 64 + w * 16;

    f32x4 acc[4] = {{0,0,0,0},{0,0,0,0},{0,0,0,0},{0,0,0,0}};

    // A operand: lane holds A[m = lane&15][k = quad*8 + j], j=0..7 contiguous
    const float* xr = x + (size_t)(rowbase + m) * IN_F + quad * 8;
    const uint4* w1p = W1f + lane;

#pragma unroll 2
    for (int k = 0; k < 24; ++k) {
        const float4 xa = *(const float4*)(xr + k * 32);
        const float4 xb = *(const float4*)(xr + k * 32 + 4);
        FragU a;
        a.u[0] = f2bf2(xa.x, xa.y);
        a.u[1] = f2bf2(xa.z, xa.w);
        a.u[2] = f2bf2(xb.x, xb.y);
        a.u[3] = f2bf2(xb.z, xb.w);
        FragU b0, b1f, b2f, b3f;
        b0.q  = w1p[(k * 4 + 0) * 64];
        b1f.q = w1p[(k * 4 + 1) * 64];
        b2f.q = w1p[(k * 4 + 2) * 64];
        b3f.q = w1p[(k * 4 + 3) * 64];
        acc[0] = __builtin_amdgcn_mfma_f32_16x16x32_bf16(a.v, b0.v,  acc[0], 0, 0, 0);
        acc[1] = __builtin_amdgcn_mfma_f32_16x16x32_bf16(a.v, b1f.v, acc[1], 0, 0, 0);
        acc[2] = __builtin_amdgcn_mfma_f32_16x16x32_bf16(a.v, b2f.v, acc[2], 0, 0, 0);
        acc[3] = __builtin_amdgcn_mfma_f32_16x16x32_bf16(a.v, b3f.v, acc[3], 0, 0, 0);
    }

    // Epilogue 1: h1 = relu(acc + b1) -> LDS as bf16.
    // C layout: col = lane&15 (+16*nt), row = quad*4 + reg.
#pragma unroll
    for (int nt = 0; nt < 4; ++nt) {
        const int col = nt * 16 + m;
        const float bias = b1[col];
#pragma unroll
        for (int r = 0; r < 4; ++r) {
            float h = acc[nt][r] + bias;
            h = h > 0.f ? h : 0.f;
            h1s[w][quad * 4 + r][col] = (uint16_t)f2bf1(h);
        }
    }
    // Same-wave RAW only (each wave reads its own h1s[w]) -> no __syncthreads needed;
    // compiler inserts the lgkmcnt wait.

    // Layer 2: 2 K-steps x 4 N-tiles
    f32x4 acc2[4] = {{0,0,0,0},{0,0,0,0},{0,0,0,0},{0,0,0,0}};
#pragma unroll
    for (int k2 = 0; k2 < 2; ++k2) {
        FragU a2;
        a2.q = *(const uint4*)&h1s[w][m][k2 * 32 + quad * 8];
#pragma unroll
        for (int nt = 0; nt < 4; ++nt) {
            FragU bb; bb.q = W2f[(k2 * 4 + nt) * 64 + lane];
            acc2[nt] = __builtin_amdgcn_mfma_f32_16x16x32_bf16(a2.v, bb.v, acc2[nt], 0, 0, 0);
        }
    }

    // Epilogue 2 + Layer 3 (fp32): p[r] = sum_j relu(h2)[row][j] * W3[j]
    float w3v[4];
#pragma unroll
    for (int nt = 0; nt < 4; ++nt) w3v[nt] = W3d[nt * 16 + m];

    float p[4] = {0.f, 0.f, 0.f, 0.f};
#pragma unroll
    for (int nt = 0; nt < 4; ++nt) {
        const float bias = b2[nt * 16 + m];
#pragma unroll
        for (int r = 0; r < 4; ++r) {
            float h = acc2[nt][r] + bias;
            h = h > 0.f ? h : 0.f;
            p[r] += h * w3v[nt];
        }
    }
    // reduce over the 16 lanes of the quad (the col dimension)
#pragma unroll
    for (int off = 1; off < 16; off <<= 1) {
#pragma unroll
        for (int r = 0; r < 4; ++r) p[r] += __shfl_xor(p[r], off, 16);
    }
    const float bb3 = b3[0];
    if (m == 0) {
#pragma unroll
        for (int r = 0; r < 4; ++r) out[rowbase + quad * 4 + r] = p[r] + bb3;
    }
}

extern "C" void kernel_launch(void* const* d_in, const int* in_sizes, int n_in,
                              void* d_out, int out_size, void* d_ws, size_t ws_size,
                              hipStream_t stream) {
    const float* x    = (const float*)d_in[0];
    const int*   idx1 = (const int*)  d_in[1];
    const float* val1 = (const float*)d_in[2];
    const float* b1   = (const float*)d_in[3];
    const int*   idx2 = (const int*)  d_in[4];
    const float* val2 = (const float*)d_in[5];
    const float* b2   = (const float*)d_in[6];
    const int*   idx3 = (const int*)  d_in[7];
    const float* val3 = (const float*)d_in[8];
    const float* b3   = (const float*)d_in[9];
    float* out = (float*)d_out;

    char* ws = (char*)d_ws;
    float* W1d = (float*)(ws + OFF_W1D);
    float* W2d = (float*)(ws + OFF_W2D);
    float* W3d = (float*)(ws + OFF_W3D);
    uint4* W1f = (uint4*)(ws + OFF_W1F);
    uint4* W2f = (uint4*)(ws + OFF_W2F);

    // zero the dense weight buffers (ws is poisoned 0xAA before every launch)
    hipMemsetAsync(d_ws, 0, OFF_W1F, stream);

    const int nnz_total = NNZ1 + NNZ2 + NNZ3;
    scatter_coo<<<(nnz_total + 255) / 256, 256, 0, stream>>>(
        idx1, val1, idx2, val2, idx3, val3, W1d, W2d, W3d);

    const int nfrag = 24 * 4 * 64 + 2 * 4 * 64;
    frag_build<<<(nfrag + 255) / 256, 256, 0, stream>>>(W1d, W2d, W1f, W2f);

    mlp_fused<<<BATCH / 64, 256, 0, stream>>>(x, W1f, W2f, W3d, b1, b2, b3, out);
}